// Round 1
// baseline (186.451 us; speedup 1.0000x reference)
//
#include <hip/hip_runtime.h>
#include <hip/hip_bf16.h>
#include <cstdint>
#include <cstddef>

typedef __bf16 bf16;
typedef bf16 bf16x4 __attribute__((ext_vector_type(4)));
typedef bf16 bf16x8 __attribute__((ext_vector_type(8)));
typedef float f32x4 __attribute__((ext_vector_type(4)));

// ---------------- prep: fp32 weights -> bf16, build qkv scale/bias ----------------
__global__ __launch_bounds__(256) void prep_kernel(
    const float* __restrict__ q_w, const float* __restrict__ kv_w,
    const float* __restrict__ proj_w, const float* __restrict__ fc1_w,
    const float* __restrict__ fc2_w, const float* __restrict__ q_b,
    const float* __restrict__ kv_b,
    bf16* __restrict__ wqkv, bf16* __restrict__ wproj,
    bf16* __restrict__ wfc1, bf16* __restrict__ wfc2,
    float* __restrict__ qscale, float* __restrict__ qbias)
{
  int i = blockIdx.x * 256 + threadIdx.x;
  if (i < 196608) wqkv[i] = (bf16)(i < 65536 ? q_w[i] : kv_w[i - 65536]);
  if (i < 65536)  wproj[i] = (bf16)proj_w[i];
  if (i < 131072) { wfc1[i] = (bf16)fc1_w[i]; wfc2[i] = (bf16)fc2_w[i]; }
  if (i < 768) {
    const float s = 0.17677669529663687f;  // 1/sqrt(32)
    qscale[i] = (i < 256) ? s : 1.0f;
    qbias[i]  = (i < 256) ? q_b[i] * s : kv_b[i - 256];
  }
}

// ---------------- layernorm: one wave per 256-elem row -> bf16 ----------------
__global__ __launch_bounds__(256) void ln_kernel(
    const float* __restrict__ in, const float* __restrict__ w,
    const float* __restrict__ b, bf16* __restrict__ out)
{
  const int wv = threadIdx.x >> 6, lane = threadIdx.x & 63;
  const int row = blockIdx.x * 4 + wv;
  f32x4 v = *((const f32x4*)(in + (size_t)row * 256) + lane);
  float s  = v[0] + v[1] + v[2] + v[3];
  float s2 = v[0]*v[0] + v[1]*v[1] + v[2]*v[2] + v[3]*v[3];
  #pragma unroll
  for (int o = 1; o < 64; o <<= 1) { s += __shfl_xor(s, o); s2 += __shfl_xor(s2, o); }
  float mu = s * (1.0f / 256.0f);
  float var = s2 * (1.0f / 256.0f) - mu * mu;
  float rstd = rsqrtf(var + 1e-5f);
  f32x4 wv4 = *((const f32x4*)w + lane);
  f32x4 bv4 = *((const f32x4*)b + lane);
  bf16x4 o4;
  o4[0] = (bf16)((v[0] - mu) * rstd * wv4[0] + bv4[0]);
  o4[1] = (bf16)((v[1] - mu) * rstd * wv4[1] + bv4[1]);
  o4[2] = (bf16)((v[2] - mu) * rstd * wv4[2] + bv4[2]);
  o4[3] = (bf16)((v[3] - mu) * rstd * wv4[3] + bv4[3]);
  *((bf16x4*)(out + (size_t)row * 256) + lane) = o4;
}

// ---------------- GEMM: C(M,N) = A(M,K) * B(N,K)^T, bf16 MFMA, fused epilogue ----------------
// 64x64 tile, BK=32, 4 waves (2x2 of 32x32). LDS layout [kpart][row][8] -> conflict-free b128 reads.
__global__ __launch_bounds__(256) void gemm_bt(
    const bf16* __restrict__ A, const bf16* __restrict__ B,
    int N, int K,
    const float* __restrict__ scale, const float* __restrict__ bias,
    const float* __restrict__ residual, int do_gelu,
    float* __restrict__ outf, bf16* __restrict__ outh)
{
  __shared__ __align__(16) bf16 ldsA[4][64][8];
  __shared__ __align__(16) bf16 ldsB[4][64][8];
  const int tid = threadIdx.x;
  const int w = tid >> 6, lane = tid & 63;
  const int rowBase = blockIdx.x * 64;
  const int colBase = blockIdx.y * 64;
  const int wr = (w >> 1) * 32, wc = (w & 1) * 32;
  const int part = lane >> 4, r16 = lane & 15;
  f32x4 acc[2][2] = {};

  const bf16* aSrc = A + (size_t)(rowBase + lane) * K + w * 8;
  const bf16* bSrc = B + (size_t)(colBase + lane) * K + w * 8;

  for (int k0 = 0; k0 < K; k0 += 32) {
    __builtin_amdgcn_global_load_lds(
        (const __attribute__((address_space(1))) uint32_t*)(aSrc + k0),
        (__attribute__((address_space(3))) uint32_t*)&ldsA[w][0][0], 16, 0, 0);
    __builtin_amdgcn_global_load_lds(
        (const __attribute__((address_space(1))) uint32_t*)(bSrc + k0),
        (__attribute__((address_space(3))) uint32_t*)&ldsB[w][0][0], 16, 0, 0);
    __syncthreads();
    bf16x8 a0 = *(const bf16x8*)&ldsA[part][wr + r16][0];
    bf16x8 a1 = *(const bf16x8*)&ldsA[part][wr + 16 + r16][0];
    bf16x8 b0 = *(const bf16x8*)&ldsB[part][wc + r16][0];
    bf16x8 b1 = *(const bf16x8*)&ldsB[part][wc + 16 + r16][0];
    acc[0][0] = __builtin_amdgcn_mfma_f32_16x16x32_bf16(a0, b0, acc[0][0], 0, 0, 0);
    acc[0][1] = __builtin_amdgcn_mfma_f32_16x16x32_bf16(a0, b1, acc[0][1], 0, 0, 0);
    acc[1][0] = __builtin_amdgcn_mfma_f32_16x16x32_bf16(a1, b0, acc[1][0], 0, 0, 0);
    acc[1][1] = __builtin_amdgcn_mfma_f32_16x16x32_bf16(a1, b1, acc[1][1], 0, 0, 0);
    __syncthreads();
  }

  #pragma unroll
  for (int fm = 0; fm < 2; ++fm)
  #pragma unroll
  for (int fn = 0; fn < 2; ++fn)
  #pragma unroll
  for (int r = 0; r < 4; ++r) {
    int row = rowBase + wr + fm * 16 + part * 4 + r;
    int col = colBase + wc + fn * 16 + r16;
    float v = acc[fm][fn][r];
    if (scale)    v *= scale[col];
    if (bias)     v += bias[col];
    if (do_gelu)  v = 0.5f * v * (1.0f + erff(v * 0.70710678118654752f));
    if (residual) v += residual[(size_t)row * N + col];
    if (outf) outf[(size_t)row * N + col] = v;
    else      outh[(size_t)row * N + col] = (bf16)v;
  }
}

// ---------------- attention: one wave per token ----------------
// lane = hh*8 + t : head hh (0..7), quarter t (0..7) of c_=32.
// qkv row layout: [0..255]=q (scaled, bias), [256..767]=kv with col = hh*64 + sel*32 + cc.
__global__ __launch_bounds__(256) void attn_kernel(
    const bf16* __restrict__ qkv,
    const int* __restrict__ member_idx,
    const int* __restrict__ pe_idx,
    const float* __restrict__ cluster_mask,
    const float* __restrict__ pre_table,
    const float* __restrict__ pe_w, const float* __restrict__ pe_b,
    const float* __restrict__ blank_k, const float* __restrict__ blank_v,
    bf16* __restrict__ out)
{
  __shared__ float lg[4][8][52];
  const int wv = threadIdx.x >> 6, lane = threadIdx.x & 63;
  const int token = blockIdx.x * 4 + wv;
  const int bb = token >> 12;
  const int hh = lane >> 3, t = lane & 7;

  bf16x4 q4 = *((const bf16x4*)(qkv + (size_t)token * 768) + lane);
  const float q0 = (float)q4[0], q1 = (float)q4[1], q2 = (float)q4[2], q3 = (float)q4[3];

  const float pw0 = pe_w[hh * 5 + 0], pw1 = pe_w[hh * 5 + 1], pw2 = pe_w[hh * 5 + 2],
              pw3 = pe_w[hh * 5 + 3], pw4 = pe_w[hh * 5 + 4], pbi = pe_b[hh];

  const int* mrow = member_idx + (size_t)token * 48;
  const int* prow = pe_idx + (size_t)token * 48;
  const float* crow = cluster_mask + (size_t)token * 48;
  const int kchunk = hh * 16 + t;       // k: offset (hh*64 + t*4)/4 within kv region
  const int vchunk = hh * 16 + 8 + t;   // v: offset (hh*64 + 32 + t*4)/4

  #pragma unroll 4
  for (int j = 0; j < 48; ++j) {
    int idx = mrow[j];
    const bf16x4* kvrow = (const bf16x4*)(qkv + ((size_t)(bb * 4096 + idx) * 768 + 256));
    bf16x4 k4 = kvrow[kchunk];
    float d = q0 * (float)k4[0] + q1 * (float)k4[1] + q2 * (float)k4[2] + q3 * (float)k4[3];
    d += __shfl_xor(d, 1); d += __shfl_xor(d, 2); d += __shfl_xor(d, 4);
    const float* pt = pre_table + (size_t)prow[j] * 5;
    float pos = pt[0] * pw0 + pt[1] * pw1 + pt[2] * pw2 + pt[3] * pw3 + pt[4] * pw4 + pbi;
    float logit = d + pos + (1.0f - crow[j]) * -100.0f;
    if (t == 0) lg[wv][hh][j] = logit;
  }
  {
    f32x4 bk = *((const f32x4*)blank_k + lane);
    float d = q0 * bk[0] + q1 * bk[1] + q2 * bk[2] + q3 * bk[3];
    d += __shfl_xor(d, 1); d += __shfl_xor(d, 2); d += __shfl_xor(d, 4);
    if (t == 0) lg[wv][hh][48] = d;
  }
  __syncthreads();

  float mx = -1e30f;
  for (int j = t; j < 49; j += 8) mx = fmaxf(mx, lg[wv][hh][j]);
  mx = fmaxf(mx, __shfl_xor(mx, 1));
  mx = fmaxf(mx, __shfl_xor(mx, 2));
  mx = fmaxf(mx, __shfl_xor(mx, 4));
  float sm = 0.0f;
  for (int j = t; j < 49; j += 8) { float e = __expf(lg[wv][hh][j] - mx); lg[wv][hh][j] = e; sm += e; }
  sm += __shfl_xor(sm, 1); sm += __shfl_xor(sm, 2); sm += __shfl_xor(sm, 4);
  float inv = 1.0f / sm;
  __syncthreads();

  f32x4 bv = *((const f32x4*)blank_v + lane);
  float bw = lg[wv][hh][48] * inv;
  float o0 = bw * bv[0], o1 = bw * bv[1], o2 = bw * bv[2], o3 = bw * bv[3];
  #pragma unroll 4
  for (int j = 0; j < 48; ++j) {
    int idx = mrow[j];
    const bf16x4* kvrow = (const bf16x4*)(qkv + ((size_t)(bb * 4096 + idx) * 768 + 256));
    bf16x4 v4 = kvrow[vchunk];
    float wj = lg[wv][hh][j] * inv;
    o0 += wj * (float)v4[0]; o1 += wj * (float)v4[1];
    o2 += wj * (float)v4[2]; o3 += wj * (float)v4[3];
  }
  bf16x4 ov; ov[0] = (bf16)o0; ov[1] = (bf16)o1; ov[2] = (bf16)o2; ov[3] = (bf16)o3;
  *((bf16x4*)(out + (size_t)token * 256) + lane) = ov;
}

// ---------------- host launcher ----------------
extern "C" void kernel_launch(void* const* d_in, const int* in_sizes, int n_in,
                              void* d_out, int out_size, void* d_ws, size_t ws_size,
                              hipStream_t stream)
{
  (void)in_sizes; (void)n_in; (void)out_size; (void)ws_size;
  const float* feat         = (const float*)d_in[0];
  const float* cluster_mask = (const float*)d_in[1];
  const float* pre_table    = (const float*)d_in[2];
  const float* norm1_w      = (const float*)d_in[3];
  const float* norm1_b      = (const float*)d_in[4];
  const float* q_w    = (const float*)d_in[5];
  const float* q_b    = (const float*)d_in[6];
  const float* kv_w   = (const float*)d_in[7];
  const float* kv_b   = (const float*)d_in[8];
  const float* blank_k = (const float*)d_in[9];
  const float* blank_v = (const float*)d_in[10];
  const float* pe_w   = (const float*)d_in[11];
  const float* pe_b   = (const float*)d_in[12];
  const float* proj_w = (const float*)d_in[13];
  const float* proj_b = (const float*)d_in[14];
  const float* norm2_w = (const float*)d_in[15];
  const float* norm2_b = (const float*)d_in[16];
  const float* fc1_w  = (const float*)d_in[17];
  const float* fc1_b  = (const float*)d_in[18];
  const float* fc2_w  = (const float*)d_in[19];
  const float* fc2_b  = (const float*)d_in[20];
  const int* member_idx = (const int*)d_in[21];
  const int* pe_idx     = (const int*)d_in[22];
  // d_in[23] = global_attn (unused, ==0)

  char* ws = (char*)d_ws;
  size_t off = 0;
  auto alloc = [&](size_t bytes) -> void* {
    void* p = ws + off; off += (bytes + 255) & ~(size_t)255; return p;
  };
  bf16*  wqkv  = (bf16*)alloc(768 * 256 * sizeof(bf16));
  bf16*  wproj = (bf16*)alloc(256 * 256 * sizeof(bf16));
  bf16*  wfc1  = (bf16*)alloc(512 * 256 * sizeof(bf16));
  bf16*  wfc2  = (bf16*)alloc(256 * 512 * sizeof(bf16));
  float* qscale = (float*)alloc(768 * sizeof(float));
  float* qbias  = (float*)alloc(768 * sizeof(float));
  bf16*  xbuf  = (bf16*)alloc((size_t)8192 * 256 * sizeof(bf16));   // x1, reused as x2
  bf16*  qkvb  = (bf16*)alloc((size_t)8192 * 768 * sizeof(bf16));   // qkv, reused as y1
  bf16*  attnb = (bf16*)alloc((size_t)8192 * 256 * sizeof(bf16));
  float* feat2 = (float*)alloc((size_t)8192 * 256 * sizeof(float));
  bf16*  y1 = qkvb;
  float* outf = (float*)d_out;

  hipLaunchKernelGGL(prep_kernel, dim3(768), dim3(256), 0, stream,
                     q_w, kv_w, proj_w, fc1_w, fc2_w, q_b, kv_b,
                     wqkv, wproj, wfc1, wfc2, qscale, qbias);
  hipLaunchKernelGGL(ln_kernel, dim3(2048), dim3(256), 0, stream,
                     feat, norm1_w, norm1_b, xbuf);
  hipLaunchKernelGGL(gemm_bt, dim3(128, 12), dim3(256), 0, stream,
                     xbuf, wqkv, 768, 256, qscale, qbias,
                     (const float*)nullptr, 0, (float*)nullptr, qkvb);
  hipLaunchKernelGGL(attn_kernel, dim3(2048), dim3(256), 0, stream,
                     qkvb, member_idx, pe_idx, cluster_mask, pre_table,
                     pe_w, pe_b, blank_k, blank_v, attnb);
  hipLaunchKernelGGL(gemm_bt, dim3(128, 4), dim3(256), 0, stream,
                     attnb, wproj, 256, 256, (const float*)nullptr, proj_b,
                     feat, 0, feat2, (bf16*)nullptr);
  hipLaunchKernelGGL(ln_kernel, dim3(2048), dim3(256), 0, stream,
                     feat2, norm2_w, norm2_b, xbuf);
  hipLaunchKernelGGL(gemm_bt, dim3(128, 8), dim3(256), 0, stream,
                     xbuf, wfc1, 512, 256, (const float*)nullptr, fc1_b,
                     (const float*)nullptr, 1, (float*)nullptr, y1);
  hipLaunchKernelGGL(gemm_bt, dim3(128, 4), dim3(256), 0, stream,
                     y1, wfc2, 256, 512, (const float*)nullptr, fc2_b,
                     feat2, 0, outf, (bf16*)nullptr);
}

// Round 2
// 124.848 us; speedup vs baseline: 1.4934x; 1.4934x over previous
//
#include <hip/hip_runtime.h>
#include <hip/hip_bf16.h>
#include <cstdint>
#include <cstddef>

typedef __bf16 bf16;
typedef bf16 bf16x4 __attribute__((ext_vector_type(4)));
typedef bf16 bf16x8 __attribute__((ext_vector_type(8)));
typedef float f32x4 __attribute__((ext_vector_type(4)));

// ---------------- prep: fp32 weights -> bf16, build qkv scale/bias ----------------
// kv weight ROWS are permuted so the qkv activation layout becomes, per head hh:
//   [hh*64 + t*8 + e]  e=0..3 -> k[cc=t*4+e], e=4..7 -> v[cc=t*4+e-4]
// i.e. each lane (hh,t) of the attention wave reads its k4+v4 as ONE 16B chunk.
__device__ __forceinline__ int kv_perm_to_orig(int nc) {
  int hh = nc >> 6, r6 = nc & 63, t = r6 >> 3, e = r6 & 7;
  int sel = e >> 2, cc = t * 4 + (e & 3);
  return hh * 64 + sel * 32 + cc;   // original kv_w row (0..511)
}

__global__ __launch_bounds__(256) void prep_kernel(
    const float* __restrict__ q_w, const float* __restrict__ kv_w,
    const float* __restrict__ proj_w, const float* __restrict__ fc1_w,
    const float* __restrict__ fc2_w, const float* __restrict__ q_b,
    const float* __restrict__ kv_b,
    bf16* __restrict__ wqkv, bf16* __restrict__ wproj,
    bf16* __restrict__ wfc1, bf16* __restrict__ wfc2,
    float* __restrict__ qscale, float* __restrict__ qbias)
{
  int i = blockIdx.x * 256 + threadIdx.x;
  if (i < 196608) {
    int row = i >> 8, col = i & 255;
    float v;
    if (row < 256) v = q_w[i];
    else           v = kv_w[kv_perm_to_orig(row - 256) * 256 + col];
    wqkv[i] = (bf16)v;
  }
  if (i < 65536)  wproj[i] = (bf16)proj_w[i];
  if (i < 131072) { wfc1[i] = (bf16)fc1_w[i]; wfc2[i] = (bf16)fc2_w[i]; }
  if (i < 768) {
    const float s = 0.17677669529663687f;  // 1/sqrt(32)
    if (i < 256) { qscale[i] = s;    qbias[i] = q_b[i] * s; }
    else         { qscale[i] = 1.0f; qbias[i] = kv_b[kv_perm_to_orig(i - 256)]; }
  }
}

// ---------------- layernorm: one wave per 256-elem row -> bf16 ----------------
__global__ __launch_bounds__(256) void ln_kernel(
    const float* __restrict__ in, const float* __restrict__ w,
    const float* __restrict__ b, bf16* __restrict__ out)
{
  const int wv = threadIdx.x >> 6, lane = threadIdx.x & 63;
  const int row = blockIdx.x * 4 + wv;
  f32x4 v = *((const f32x4*)(in + (size_t)row * 256) + lane);
  float s  = v[0] + v[1] + v[2] + v[3];
  float s2 = v[0]*v[0] + v[1]*v[1] + v[2]*v[2] + v[3]*v[3];
  #pragma unroll
  for (int o = 1; o < 64; o <<= 1) { s += __shfl_xor(s, o); s2 += __shfl_xor(s2, o); }
  float mu = s * (1.0f / 256.0f);
  float var = s2 * (1.0f / 256.0f) - mu * mu;
  float rstd = rsqrtf(var + 1e-5f);
  f32x4 wv4 = *((const f32x4*)w + lane);
  f32x4 bv4 = *((const f32x4*)b + lane);
  bf16x4 o4;
  o4[0] = (bf16)((v[0] - mu) * rstd * wv4[0] + bv4[0]);
  o4[1] = (bf16)((v[1] - mu) * rstd * wv4[1] + bv4[1]);
  o4[2] = (bf16)((v[2] - mu) * rstd * wv4[2] + bv4[2]);
  o4[3] = (bf16)((v[3] - mu) * rstd * wv4[3] + bv4[3]);
  *((bf16x4*)(out + (size_t)row * 256) + lane) = o4;
}

// ---------------- GEMM: C(M,N) = A(M,K) * B(N,K)^T, bf16 MFMA, fused epilogue ----------------
__global__ __launch_bounds__(256) void gemm_bt(
    const bf16* __restrict__ A, const bf16* __restrict__ B,
    int N, int K,
    const float* __restrict__ scale, const float* __restrict__ bias,
    const float* __restrict__ residual, int do_gelu,
    float* __restrict__ outf, bf16* __restrict__ outh)
{
  __shared__ __align__(16) bf16 ldsA[4][64][8];
  __shared__ __align__(16) bf16 ldsB[4][64][8];
  const int tid = threadIdx.x;
  const int w = tid >> 6, lane = tid & 63;
  const int rowBase = blockIdx.x * 64;
  const int colBase = blockIdx.y * 64;
  const int wr = (w >> 1) * 32, wc = (w & 1) * 32;
  const int part = lane >> 4, r16 = lane & 15;
  f32x4 acc[2][2] = {};

  const bf16* aSrc = A + (size_t)(rowBase + lane) * K + w * 8;
  const bf16* bSrc = B + (size_t)(colBase + lane) * K + w * 8;

  for (int k0 = 0; k0 < K; k0 += 32) {
    __builtin_amdgcn_global_load_lds(
        (const __attribute__((address_space(1))) uint32_t*)(aSrc + k0),
        (__attribute__((address_space(3))) uint32_t*)&ldsA[w][0][0], 16, 0, 0);
    __builtin_amdgcn_global_load_lds(
        (const __attribute__((address_space(1))) uint32_t*)(bSrc + k0),
        (__attribute__((address_space(3))) uint32_t*)&ldsB[w][0][0], 16, 0, 0);
    __syncthreads();
    bf16x8 a0 = *(const bf16x8*)&ldsA[part][wr + r16][0];
    bf16x8 a1 = *(const bf16x8*)&ldsA[part][wr + 16 + r16][0];
    bf16x8 b0 = *(const bf16x8*)&ldsB[part][wc + r16][0];
    bf16x8 b1 = *(const bf16x8*)&ldsB[part][wc + 16 + r16][0];
    acc[0][0] = __builtin_amdgcn_mfma_f32_16x16x32_bf16(a0, b0, acc[0][0], 0, 0, 0);
    acc[0][1] = __builtin_amdgcn_mfma_f32_16x16x32_bf16(a0, b1, acc[0][1], 0, 0, 0);
    acc[1][0] = __builtin_amdgcn_mfma_f32_16x16x32_bf16(a1, b0, acc[1][0], 0, 0, 0);
    acc[1][1] = __builtin_amdgcn_mfma_f32_16x16x32_bf16(a1, b1, acc[1][1], 0, 0, 0);
    __syncthreads();
  }

  #pragma unroll
  for (int fm = 0; fm < 2; ++fm)
  #pragma unroll
  for (int fn = 0; fn < 2; ++fn)
  #pragma unroll
  for (int r = 0; r < 4; ++r) {
    int row = rowBase + wr + fm * 16 + part * 4 + r;
    int col = colBase + wc + fn * 16 + r16;
    float v = acc[fm][fn][r];
    if (scale)    v *= scale[col];
    if (bias)     v += bias[col];
    if (do_gelu)  v = 0.5f * v * (1.0f + erff(v * 0.70710678118654752f));
    if (residual) v += residual[(size_t)row * N + col];
    if (outf) outf[(size_t)row * N + col] = v;
    else      outh[(size_t)row * N + col] = (bf16)v;
  }
}

// ---------------- attention: one wave per token, single-pass online softmax ----------------
// lane = hh*8 + t. qkv row: [0..255]=q (scaled+bias), [256..767]=kv interleaved so lane
// reads k4|v4 as one 16B chunk at elem offset 256 + lane*8.
__global__ __launch_bounds__(256) void attn_kernel(
    const bf16* __restrict__ qkv,
    const int* __restrict__ member_idx,
    const int* __restrict__ pe_idx,
    const float* __restrict__ cluster_mask,
    const float* __restrict__ pre_table,
    const float* __restrict__ pe_w, const float* __restrict__ pe_b,
    const float* __restrict__ blank_k, const float* __restrict__ blank_v,
    bf16* __restrict__ out)
{
  __shared__ float posm[4][48][8];   // [wave][j][head]: pos + mask term
  const int wv = threadIdx.x >> 6, lane = threadIdx.x & 63;
  const int token = blockIdx.x * 4 + wv;
  const int bb = token >> 12;
  const int hh = lane >> 3;

  // q fragment: 4 consecutive elems (hh*32 + t*4 ..)
  bf16x4 q4 = *((const bf16x4*)(qkv + (size_t)token * 768) + lane);
  const float q0 = (float)q4[0], q1 = (float)q4[1], q2 = (float)q4[2], q3 = (float)q4[3];

  // parallel preload of per-neighbor metadata (lane j owns neighbor j)
  const int jl = (lane < 48) ? lane : 0;
  int idx_lane = member_idx[(size_t)token * 48 + jl];
  if (lane < 48) {
    int pj = pe_idx[(size_t)token * 48 + lane];
    const float* pt = pre_table + (size_t)pj * 5;
    float p0 = pt[0], p1 = pt[1], p2 = pt[2], p3 = pt[3], p4 = pt[4];
    float mk = (1.0f - cluster_mask[(size_t)token * 48 + lane]) * -100.0f;
    #pragma unroll
    for (int h = 0; h < 8; ++h) {
      float pos = p0 * pe_w[h*5+0] + p1 * pe_w[h*5+1] + p2 * pe_w[h*5+2]
                + p3 * pe_w[h*5+3] + p4 * pe_w[h*5+4] + pe_b[h] + mk;
      posm[wv][lane][h] = pos;
    }
  }

  // blank token initializes the online-softmax state
  f32x4 bk = *((const f32x4*)blank_k + lane);
  float db = q0 * bk[0] + q1 * bk[1] + q2 * bk[2] + q3 * bk[3];
  db += __shfl_xor(db, 1); db += __shfl_xor(db, 2); db += __shfl_xor(db, 4);
  float m = db, l = 1.0f;
  f32x4 bv = *((const f32x4*)blank_v + lane);
  float o0 = bv[0], o1 = bv[1], o2 = bv[2], o3 = bv[3];

  __syncthreads();

  const bf16* kvbase = qkv + (size_t)(bb * 4096) * 768 + 256;
  #pragma unroll 8
  for (int j = 0; j < 48; ++j) {
    int idx = __shfl(idx_lane, j);
    bf16x8 kv8 = *((const bf16x8*)(kvbase + (size_t)idx * 768) + lane);
    float d = (float)kv8[0] * q0 + (float)kv8[1] * q1
            + (float)kv8[2] * q2 + (float)kv8[3] * q3;
    d += __shfl_xor(d, 1); d += __shfl_xor(d, 2); d += __shfl_xor(d, 4);
    float logit = d + posm[wv][j][hh];
    float mn = fmaxf(m, logit);
    float sc = __expf(m - mn);
    float p  = __expf(logit - mn);
    l = l * sc + p;
    o0 = o0 * sc + p * (float)kv8[4];
    o1 = o1 * sc + p * (float)kv8[5];
    o2 = o2 * sc + p * (float)kv8[6];
    o3 = o3 * sc + p * (float)kv8[7];
    m = mn;
  }
  float inv = 1.0f / l;
  bf16x4 ov;
  ov[0] = (bf16)(o0 * inv); ov[1] = (bf16)(o1 * inv);
  ov[2] = (bf16)(o2 * inv); ov[3] = (bf16)(o3 * inv);
  *((bf16x4*)(out + (size_t)token * 256) + lane) = ov;
}

// ---------------- host launcher ----------------
extern "C" void kernel_launch(void* const* d_in, const int* in_sizes, int n_in,
                              void* d_out, int out_size, void* d_ws, size_t ws_size,
                              hipStream_t stream)
{
  (void)in_sizes; (void)n_in; (void)out_size; (void)ws_size;
  const float* feat         = (const float*)d_in[0];
  const float* cluster_mask = (const float*)d_in[1];
  const float* pre_table    = (const float*)d_in[2];
  const float* norm1_w      = (const float*)d_in[3];
  const float* norm1_b      = (const float*)d_in[4];
  const float* q_w    = (const float*)d_in[5];
  const float* q_b    = (const float*)d_in[6];
  const float* kv_w   = (const float*)d_in[7];
  const float* kv_b   = (const float*)d_in[8];
  const float* blank_k = (const float*)d_in[9];
  const float* blank_v = (const float*)d_in[10];
  const float* pe_w   = (const float*)d_in[11];
  const float* pe_b   = (const float*)d_in[12];
  const float* proj_w = (const float*)d_in[13];
  const float* proj_b = (const float*)d_in[14];
  const float* norm2_w = (const float*)d_in[15];
  const float* norm2_b = (const float*)d_in[16];
  const float* fc1_w  = (const float*)d_in[17];
  const float* fc1_b  = (const float*)d_in[18];
  const float* fc2_w  = (const float*)d_in[19];
  const float* fc2_b  = (const float*)d_in[20];
  const int* member_idx = (const int*)d_in[21];
  const int* pe_idx     = (const int*)d_in[22];

  char* ws = (char*)d_ws;
  size_t off = 0;
  auto alloc = [&](size_t bytes) -> void* {
    void* p = ws + off; off += (bytes + 255) & ~(size_t)255; return p;
  };
  bf16*  wqkv  = (bf16*)alloc(768 * 256 * sizeof(bf16));
  bf16*  wproj = (bf16*)alloc(256 * 256 * sizeof(bf16));
  bf16*  wfc1  = (bf16*)alloc(512 * 256 * sizeof(bf16));
  bf16*  wfc2  = (bf16*)alloc(256 * 512 * sizeof(bf16));
  float* qscale = (float*)alloc(768 * sizeof(float));
  float* qbias  = (float*)alloc(768 * sizeof(float));
  bf16*  xbuf  = (bf16*)alloc((size_t)8192 * 256 * sizeof(bf16));   // x1, reused as x2
  bf16*  qkvb  = (bf16*)alloc((size_t)8192 * 768 * sizeof(bf16));   // qkv, reused as y1
  bf16*  attnb = (bf16*)alloc((size_t)8192 * 256 * sizeof(bf16));
  float* feat2 = (float*)alloc((size_t)8192 * 256 * sizeof(float));
  bf16*  y1 = qkvb;
  float* outf = (float*)d_out;

  hipLaunchKernelGGL(prep_kernel, dim3(768), dim3(256), 0, stream,
                     q_w, kv_w, proj_w, fc1_w, fc2_w, q_b, kv_b,
                     wqkv, wproj, wfc1, wfc2, qscale, qbias);
  hipLaunchKernelGGL(ln_kernel, dim3(2048), dim3(256), 0, stream,
                     feat, norm1_w, norm1_b, xbuf);
  hipLaunchKernelGGL(gemm_bt, dim3(128, 12), dim3(256), 0, stream,
                     xbuf, wqkv, 768, 256, qscale, qbias,
                     (const float*)nullptr, 0, (float*)nullptr, qkvb);
  hipLaunchKernelGGL(attn_kernel, dim3(2048), dim3(256), 0, stream,
                     qkvb, member_idx, pe_idx, cluster_mask, pre_table,
                     pe_w, pe_b, blank_k, blank_v, attnb);
  hipLaunchKernelGGL(gemm_bt, dim3(128, 4), dim3(256), 0, stream,
                     attnb, wproj, 256, 256, (const float*)nullptr, proj_b,
                     feat, 0, feat2, (bf16*)nullptr);
  hipLaunchKernelGGL(ln_kernel, dim3(2048), dim3(256), 0, stream,
                     feat2, norm2_w, norm2_b, xbuf);
  hipLaunchKernelGGL(gemm_bt, dim3(128, 8), dim3(256), 0, stream,
                     xbuf, wfc1, 512, 256, (const float*)nullptr, fc1_b,
                     (const float*)nullptr, 1, (float*)nullptr, y1);
  hipLaunchKernelGGL(gemm_bt, dim3(128, 4), dim3(256), 0, stream,
                     y1, wfc2, 256, 512, (const float*)nullptr, fc2_b,
                     feat2, 0, outf, (bf16*)nullptr);
}